// Round 3
// baseline (209.586 us; speedup 1.0000x reference)
//
#include <hip/hip_runtime.h>
#include <hip/hip_bf16.h>
#include <math.h>

constexpr int B = 16, S = 2048, D = 128, H = 8, NM = 4;
constexpr int KS = 4;          // K-split for G kernel (grid.y)
constexpr int TS = S / KS;     // 512 t per block
constexpr int BK = 64;         // t per staged iteration
constexpr int BKP = BK + 8;    // padded LDS row (bf16) = 72 el = 144 B

typedef __bf16  bf16x8 __attribute__((ext_vector_type(8)));
typedef float  f32x16 __attribute__((ext_vector_type(16)));

union PackU4 { __hip_bfloat162 h2[4]; uint4 u4; };
union PackU1 { __hip_bfloat162 h2;    unsigned int u; };

// ---------------------------------------------------------------------------
// A1 (v2): per (b, 64-row t-tile): stage x tile (stride-129 pad); compute
// f = sigmoid(x@Wf+bf) for all 8 heads (coalesced fw writes); write bf16
// TRANSPOSED x -> xT[b][i][t] with FULL-LINE coalesced stores:
// lane -> (igrp=tid>>3 rows, tchunk=tid&7 t-chunks) => 8 consecutive lanes
// write one full 128B line. LDS reads hit all 32 banks (stride 129).
// ---------------------------------------------------------------------------
__global__ __launch_bounds__(256, 4) void a1_kernel(
    const float* __restrict__ x, const float* __restrict__ Wf,
    const float* __restrict__ bfv, float* __restrict__ fw,
    ushort* __restrict__ xTu)
{
    __shared__ float sX[64][129];    // 33 KB
    __shared__ float sWf[D * H];     // 4 KB

    const int b  = blockIdx.x >> 5;
    const int t0 = (blockIdx.x & 31) << 6;
    const int tid = threadIdx.x;

    for (int e = tid; e < D * H; e += 256) sWf[e] = Wf[e];

    // load 64 x 128 tile, coalesced float4
    #pragma unroll
    for (int q = 0; q < 8; ++q) {
        const int e = q * 256 + tid;             // float4 index 0..2047
        const int row = e >> 5, c4 = (e & 31) * 4;
        *(float4*)&sX[row][c4] =
            *(const float4*)&x[((size_t)(b * S) + t0 + row) * D + c4];
    }
    __syncthreads();

    // ---- f projection: thread (r = tid>>2, dq = tid&3 -> 32-d quarter) ----
    {
        const int r = tid >> 2, dq = tid & 3;
        float acch[8] = {0.f,0.f,0.f,0.f,0.f,0.f,0.f,0.f};
        for (int d4 = 0; d4 < 32; d4 += 4) {
            const int d = dq * 32 + d4;
            const float4 xv = *(const float4*)&sX[r][d];
            const float xc[4] = {xv.x, xv.y, xv.z, xv.w};
            #pragma unroll
            for (int c = 0; c < 4; ++c) {
                const float4 wa = *(const float4*)&sWf[(d + c) * 8];
                const float4 wb = *(const float4*)&sWf[(d + c) * 8 + 4];
                acch[0] += xc[c] * wa.x; acch[1] += xc[c] * wa.y;
                acch[2] += xc[c] * wa.z; acch[3] += xc[c] * wa.w;
                acch[4] += xc[c] * wb.x; acch[5] += xc[c] * wb.y;
                acch[6] += xc[c] * wb.z; acch[7] += xc[c] * wb.w;
            }
        }
        #pragma unroll
        for (int hh = 0; hh < 8; ++hh) {
            float tot = acch[hh] + __shfl_xor(acch[hh], 1);
            tot += __shfl_xor(tot, 2);
            if (dq == 0) {
                const float z = tot + bfv[hh];
                fw[((size_t)(b * H + hh)) * S + t0 + r] = 1.f / (1.f + expf(-z));
            }
        }
    }

    // ---- transposed bf16 write, full-line coalesced ----
    {
        const int tchunk = tid & 7;     // 8 t per chunk
        const int ig     = tid >> 3;    // 32 rows per pass
        #pragma unroll
        for (int pass = 0; pass < 4; ++pass) {
            const int i = pass * 32 + ig;
            float f[8];
            #pragma unroll
            for (int j = 0; j < 8; ++j) f[j] = sX[tchunk * 8 + j][i];
            PackU4 pk;
            #pragma unroll
            for (int q = 0; q < 4; ++q)
                pk.h2[q] = __float22bfloat162_rn(make_float2(f[2*q], f[2*q+1]));
            *(uint4*)&xTu[(size_t)(b * D + i) * S + t0 + tchunk * 8] = pk.u4;
        }
    }
}

// ---------------------------------------------------------------------------
// A2: per (b,h): suffix-product scan of f over S; a[t] = w_t * prod_{u>t} f_u;
// fall = prod_t f_t; suma = sum_t a_t.
// ---------------------------------------------------------------------------
__global__ __launch_bounds__(256, 2) void a2_kernel(
    const float* __restrict__ fw, const float* __restrict__ router,
    const int* __restrict__ mem_id, float* __restrict__ a,
    float* __restrict__ fallp, float* __restrict__ sumap)
{
    __shared__ float sC[257];
    __shared__ float sR[4];
    const int bh = blockIdx.x, b = bh >> 3;
    const int tid = threadIdx.x;

    float f[8];
    const float* frow = fw + (size_t)bh * S + tid * 8;
    const float4 fa = *(const float4*)frow;
    const float4 fb = *(const float4*)(frow + 4);
    f[0]=fa.x; f[1]=fa.y; f[2]=fa.z; f[3]=fa.w;
    f[4]=fb.x; f[5]=fb.y; f[6]=fb.z; f[7]=fb.w;

    float p = f[0];
    #pragma unroll
    for (int u = 1; u < 8; ++u) p *= f[u];
    sC[tid] = p;
    __syncthreads();

    for (int off = 1; off < 256; off <<= 1) {
        const float v = (tid + off < 256) ? sC[tid + off] : 1.f;
        __syncthreads();
        sC[tid] *= v;
        __syncthreads();
    }
    const float E = (tid < 255) ? sC[tid + 1] : 1.f;
    const int mid = mem_id[0];

    float aa[8];
    float s = 1.f;
    #pragma unroll
    for (int u = 7; u >= 0; --u) { aa[u] = s * E; s *= f[u]; }

    float lsum = 0.f;
    #pragma unroll
    for (int u = 0; u < 8; ++u) {
        const int t = tid * 8 + u;
        const float w = router[((size_t)(b * S) + t) * NM + mid];
        const float av = aa[u] * w;
        a[(size_t)bh * S + t] = av;
        lsum += av;
    }
    for (int off = 32; off; off >>= 1) lsum += __shfl_down(lsum, off);
    if ((tid & 63) == 0) sR[tid >> 6] = lsum;
    __syncthreads();
    if (tid == 0) { sumap[bh] = sR[0] + sR[1] + sR[2] + sR[3]; fallp[bh] = sC[0]; }
}

// ---------------------------------------------------------------------------
// gemmG: per (bh, ks): G_part = sum_{t in slice} a_t * x_t x_t^T via bf16
// MFMA 32x32x16. A = a-scaled x (scaled+rounded at staging), B = raw bf16 x.
// Also accumulates s_vec = sum_t a_t x_t (atomics).
// ---------------------------------------------------------------------------
__global__ __launch_bounds__(256, 2) void gemmG_kernel(
    const ushort* __restrict__ xTu, const float* __restrict__ a,
    float* __restrict__ Gp, float* __restrict__ sv)
{
    __shared__ ushort sA[128][BKP];
    __shared__ ushort sXx[128][BKP];
    __shared__ float  sAv[TS];
    __shared__ float  sRed[256];

    const int bh = blockIdx.x;
    const int b  = bh >> 3;
    const int ks = blockIdx.y;
    const int tid = threadIdx.x;

    const float* a_bh = a + (size_t)bh * S + ks * TS;
    sAv[tid]       = a_bh[tid];
    sAv[tid + 256] = a_bh[tid + 256];
    __syncthreads();

    const int th = tid >> 7;
    const int i  = tid & 127;
    const ushort* xrow = xTu + (size_t)(b * D + i) * S;

    const int lane = tid & 63, wid = tid >> 6;
    const int wrow = wid >> 1, wcol = wid & 1;
    const int m = lane & 31, half = lane >> 5;

    float svacc = 0.f;
    f32x16 acc00 = {}, acc01 = {}, acc10 = {}, acc11 = {};

    for (int it = 0; it < TS / BK; ++it) {
        const int tloc = it * BK + th * 32;
        uint4 r[4];
        #pragma unroll
        for (int u = 0; u < 4; ++u)
            r[u] = *(const uint4*)(xrow + ks * TS + tloc + u * 8);
        float av[32];
        #pragma unroll
        for (int q = 0; q < 8; ++q) {
            const float4 a4 = *(const float4*)&sAv[tloc + q * 4];
            av[q*4+0] = a4.x; av[q*4+1] = a4.y; av[q*4+2] = a4.z; av[q*4+3] = a4.w;
        }
        __syncthreads();
        #pragma unroll
        for (int u = 0; u < 4; ++u) {
            *(uint4*)&sXx[i][th * 32 + u * 8] = r[u];
            const unsigned int w[4] = {r[u].x, r[u].y, r[u].z, r[u].w};
            unsigned int o[4];
            #pragma unroll
            for (int q = 0; q < 4; ++q) {
                const float f0 = __uint_as_float(w[q] << 16);
                const float f1 = __uint_as_float(w[q] & 0xffff0000u);
                const float g0 = f0 * av[u * 8 + 2 * q];
                const float g1 = f1 * av[u * 8 + 2 * q + 1];
                svacc += g0 + g1;
                PackU1 pk;
                pk.h2 = __float22bfloat162_rn(make_float2(g0, g1));
                o[q] = pk.u;
            }
            *(uint4*)&sA[i][th * 32 + u * 8] = make_uint4(o[0], o[1], o[2], o[3]);
        }
        __syncthreads();
        #pragma unroll
        for (int kstep = 0; kstep < 4; ++kstep) {
            const int koff = kstep * 16 + half * 8;
            const bf16x8 a0 = *(const bf16x8*)&sA [wrow * 64 +      m][koff];
            const bf16x8 a1 = *(const bf16x8*)&sA [wrow * 64 + 32 + m][koff];
            const bf16x8 b0 = *(const bf16x8*)&sXx[wcol * 64 +      m][koff];
            const bf16x8 b1 = *(const bf16x8*)&sXx[wcol * 64 + 32 + m][koff];
            acc00 = __builtin_amdgcn_mfma_f32_32x32x16_bf16(a0, b0, acc00, 0, 0, 0);
            acc01 = __builtin_amdgcn_mfma_f32_32x32x16_bf16(a0, b1, acc01, 0, 0, 0);
            acc10 = __builtin_amdgcn_mfma_f32_32x32x16_bf16(a1, b0, acc10, 0, 0, 0);
            acc11 = __builtin_amdgcn_mfma_f32_32x32x16_bf16(a1, b1, acc11, 0, 0, 0);
        }
    }

    // C/D layout (m74/m101): col = lane&31, row = (r&3)+8*(r>>2)+4*half
    float* gp = Gp + (size_t)(ks * B * H + bh) * (D * D);
    #pragma unroll
    for (int rg = 0; rg < 16; ++rg) {
        const int rowl = (rg & 3) + 8 * (rg >> 2) + 4 * half;
        gp[(wrow * 64 +      rowl) * D + wcol * 64 +      m] = acc00[rg];
        gp[(wrow * 64 +      rowl) * D + wcol * 64 + 32 + m] = acc01[rg];
        gp[(wrow * 64 + 32 + rowl) * D + wcol * 64 +      m] = acc10[rg];
        gp[(wrow * 64 + 32 + rowl) * D + wcol * 64 + 32 + m] = acc11[rg];
    }

    sRed[tid] = svacc;
    __syncthreads();
    if (tid < 128)
        unsafeAtomicAdd(&sv[(size_t)bh * D + tid], sRed[tid] + sRed[tid + 128]);
}

// ---------------------------------------------------------------------------
// final: per (bh, col-half): C = Wk^T (G Wv) + u*bv^T + bk*w^T + suma*bk*bv^T
// + fall*M0. fp32 VALU; G symmetry -> all LDS reads row-major float4.
// ---------------------------------------------------------------------------
__global__ __launch_bounds__(256, 1) void final_kernel(
    const float* __restrict__ Gp, const float* __restrict__ Wk,
    const float* __restrict__ bk, const float* __restrict__ Wv,
    const float* __restrict__ bv, const float* __restrict__ sv,
    const float* __restrict__ fallp, const float* __restrict__ sumap,
    const float* __restrict__ M0, float* __restrict__ out)
{
    __shared__ float sA[128][132];
    __shared__ float sB[128][132];
    __shared__ float sSv[128];

    const int bh = blockIdx.x >> 1, hf = blockIdx.x & 1;
    const int h  = bh & 7;
    const int tid = threadIdx.x;

    #pragma unroll
    for (int q = 0; q < 16; ++q) {
        const int flat = q * 256 + tid;
        const int row = flat >> 5, c4 = (flat & 31) * 4;
        const size_t off = (size_t)bh * (D * D) + row * D + c4;
        float4 g = *(const float4*)&Gp[off];
        #pragma unroll
        for (int k = 1; k < KS; ++k) {
            const float4 g2 = *(const float4*)&Gp[(size_t)k * B * H * D * D + off];
            g.x += g2.x; g.y += g2.y; g.z += g2.z; g.w += g2.w;
        }
        *(float4*)&sA[row][c4] = g;
    }
    #pragma unroll
    for (int q = 0; q < 8; ++q) {
        const int flat = q * 256 + tid;
        const int l = flat >> 4, c4 = (flat & 15) * 4;
        *(float4*)&sB[l][c4] =
            *(const float4*)&Wv[(size_t)l * (D * H) + h * D + hf * 64 + c4];
    }
    if (tid < 128) sSv[tid] = sv[(size_t)bh * D + tid];
    __syncthreads();

    const int r0 = (tid >> 3) * 4, c0 = (tid & 7) * 8;

    float P[4][8] = {};
    float wv8[8] = {};
    for (int l = 0; l < 128; ++l) {
        const float4 g  = *(const float4*)&sA[l][r0];
        const float4 w0 = *(const float4*)&sB[l][c0];
        const float4 w1 = *(const float4*)&sB[l][c0 + 4];
        const float sl = sSv[l];
        const float gg[4] = {g.x, g.y, g.z, g.w};
        const float ww[8] = {w0.x,w0.y,w0.z,w0.w,w1.x,w1.y,w1.z,w1.w};
        #pragma unroll
        for (int dr = 0; dr < 4; ++dr)
            #pragma unroll
            for (int dc = 0; dc < 8; ++dc) P[dr][dc] += gg[dr] * ww[dc];
        #pragma unroll
        for (int dc = 0; dc < 8; ++dc) wv8[dc] += sl * ww[dc];
    }
    __syncthreads();

    #pragma unroll
    for (int dr = 0; dr < 4; ++dr) {
        *(float4*)&sA[r0 + dr][c0]     = make_float4(P[dr][0], P[dr][1], P[dr][2], P[dr][3]);
        *(float4*)&sA[r0 + dr][c0 + 4] = make_float4(P[dr][4], P[dr][5], P[dr][6], P[dr][7]);
    }
    #pragma unroll
    for (int q = 0; q < 16; ++q) {
        const int flat = q * 256 + tid;
        const int k = flat >> 5, c4 = (flat & 31) * 4;
        *(float4*)&sB[k][c4] = *(const float4*)&Wk[(size_t)k * (D * H) + h * D + c4];
    }
    __syncthreads();

    float C[4][8] = {};
    float u4[4] = {};
    for (int k = 0; k < 128; ++k) {
        const float4 wk = *(const float4*)&sB[k][r0];
        const float4 p0 = *(const float4*)&sA[k][c0];
        const float4 p1 = *(const float4*)&sA[k][c0 + 4];
        const float svk = sSv[k];
        const float wkk[4] = {wk.x, wk.y, wk.z, wk.w};
        const float pp[8] = {p0.x,p0.y,p0.z,p0.w,p1.x,p1.y,p1.z,p1.w};
        #pragma unroll
        for (int di = 0; di < 4; ++di) {
            #pragma unroll
            for (int dc = 0; dc < 8; ++dc) C[di][dc] += wkk[di] * pp[dc];
            u4[di] += wkk[di] * svk;
        }
    }

    const float fallv = fallp[bh], sumav = sumap[bh];
    float bkv[4], bvv[8];
    #pragma unroll
    for (int di = 0; di < 4; ++di) bkv[di] = bk[h * D + r0 + di];
    #pragma unroll
    for (int dc = 0; dc < 8; ++dc) bvv[dc] = bv[h * D + hf * 64 + c0 + dc];

    const float* m0p = M0 + (size_t)bh * (D * D);
    float* op = out + (size_t)bh * (D * D);
    #pragma unroll
    for (int di = 0; di < 4; ++di)
        #pragma unroll
        for (int dc = 0; dc < 8; ++dc) {
            const size_t idx = (size_t)(r0 + di) * D + hf * 64 + c0 + dc;
            op[idx] = C[di][dc] + u4[di] * bvv[dc] + bkv[di] * wv8[dc]
                    + sumav * bkv[di] * bvv[dc] + fallv * m0p[idx];
        }
}

extern "C" void kernel_launch(void* const* d_in, const int* in_sizes, int n_in,
                              void* d_out, int out_size, void* d_ws, size_t ws_size,
                              hipStream_t stream) {
    const float* x      = (const float*)d_in[0];
    const float* M0     = (const float*)d_in[1];
    const float* router = (const float*)d_in[2];
    const int*   mem_id = (const int*)d_in[3];
    const float* Wk     = (const float*)d_in[4];
    const float* bk     = (const float*)d_in[5];
    const float* Wv     = (const float*)d_in[6];
    const float* bv     = (const float*)d_in[7];
    const float* Wf     = (const float*)d_in[8];
    const float* bf     = (const float*)d_in[9];
    float* out = (float*)d_out;

    char* ws = (char*)d_ws;
    ushort* xTu  = (ushort*)ws;                              // 8 MB  bf16 x^T
    float*  fw   = (float*)(ws + (8u << 20));                // 1 MB  f gates
    float*  a    = (float*)(ws + (9u << 20));                // 1 MB  a_t
    float*  sv   = (float*)(ws + (10u << 20));               // 64 KB s_vec
    float*  fall = (float*)(ws + (10u << 20) + (1u << 16));
    float*  suma = (float*)(ws + (10u << 20) + (1u << 16) + 4096);
    float*  Gp   = (float*)(ws + (11u << 20));               // 32 MB G partials

    hipMemsetAsync(sv, 0, (size_t)B * H * D * sizeof(float), stream);
    a1_kernel<<<16 * 32, 256, 0, stream>>>(x, Wf, bf, fw, xTu);
    a2_kernel<<<B * H, 256, 0, stream>>>(fw, router, mem_id, a, fall, suma);
    gemmG_kernel<<<dim3(B * H, KS), 256, 0, stream>>>(xTu, a, Gp, sv);
    final_kernel<<<2 * B * H, 256, 0, stream>>>(Gp, Wk, bk, Wv, bv, sv,
                                                fall, suma, M0, out);
}

// Round 4
// 151.889 us; speedup vs baseline: 1.3799x; 1.3799x over previous
//
#include <hip/hip_runtime.h>
#include <hip/hip_bf16.h>
#include <math.h>

constexpr int B = 16, S = 2048, D = 128, H = 8, NM = 4;
constexpr int KS = 4;          // K-split for G kernel (grid.y)
constexpr int TS = S / KS;     // 512 t per block
constexpr int BK = 64;         // t per staged iteration
constexpr int BKP = BK + 8;    // padded LDS row (bf16) = 72 el = 144 B

typedef __bf16  bf16x8 __attribute__((ext_vector_type(8)));
typedef float  f32x16 __attribute__((ext_vector_type(16)));

union PackU2 { __hip_bfloat162 h2[2]; uint2 u2; };
union PackU1 { __hip_bfloat162 h2;    unsigned int u; };

// ---------------------------------------------------------------------------
// A1 (round-2 version, measured warm ~18us): per (b, 128-row t-tile): stage x
// tile in LDS; f = sigmoid(x@Wf+bf) -> fw; bf16 transposed x -> xT[b][i][t].
// (Round-3 "full-line" rewrite regressed 18->70us; reverted.)
// ---------------------------------------------------------------------------
__global__ __launch_bounds__(256, 2) void a1_kernel(
    const float* __restrict__ x, const float* __restrict__ Wf,
    const float* __restrict__ bfv, float* __restrict__ fw,
    ushort* __restrict__ xTu)
{
    __shared__ float sX[128][132];   // 67.6 KB, +4 pad
    __shared__ float sWf[D * H];     // 4 KB

    const int b  = blockIdx.x >> 4;
    const int t0 = (blockIdx.x & 15) << 7;
    const int tid = threadIdx.x;

    for (int e = tid; e < D * H; e += 256) sWf[e] = Wf[e];

    #pragma unroll
    for (int q = 0; q < 16; ++q) {
        const int e = q * 256 + tid;
        const int row = e >> 5, c4 = (e & 31) * 4;
        *(float4*)&sX[row][c4] =
            *(const float4*)&x[((size_t)(b * S) + t0 + row) * D + c4];
    }
    __syncthreads();

    // ---- f projection: thread pair (r, d-half) ----
    {
        const int r = tid >> 1, dh = tid & 1;
        float acch[8] = {0.f,0.f,0.f,0.f,0.f,0.f,0.f,0.f};
        for (int d4 = 0; d4 < 64; d4 += 4) {
            const int d = dh * 64 + d4;
            const float4 xv = *(const float4*)&sX[r][d];
            const float xc[4] = {xv.x, xv.y, xv.z, xv.w};
            #pragma unroll
            for (int c = 0; c < 4; ++c) {
                const float4 wa = *(const float4*)&sWf[(d + c) * 8];
                const float4 wb = *(const float4*)&sWf[(d + c) * 8 + 4];
                acch[0] += xc[c] * wa.x; acch[1] += xc[c] * wa.y;
                acch[2] += xc[c] * wa.z; acch[3] += xc[c] * wa.w;
                acch[4] += xc[c] * wb.x; acch[5] += xc[c] * wb.y;
                acch[6] += xc[c] * wb.z; acch[7] += xc[c] * wb.w;
            }
        }
        #pragma unroll
        for (int hh = 0; hh < 8; ++hh) {
            const float tot = acch[hh] + __shfl_xor(acch[hh], 1);
            if (dh == 0) {
                const float z = tot + bfv[hh];
                fw[((size_t)(b * H + hh)) * S + t0 + r] = 1.f / (1.f + expf(-z));
            }
        }
    }

    // ---- transposed bf16 write: thread (i, t-half) ----
    {
        const int i = tid >> 1, th = tid & 1;
        ushort* dst = xTu + (size_t)(b * D + i) * S + t0 + th * 64;
        #pragma unroll
        for (int tq = 0; tq < 16; ++tq) {
            const int t = th * 64 + tq * 4;
            const float f0 = sX[t + 0][i], f1 = sX[t + 1][i];
            const float f2 = sX[t + 2][i], f3 = sX[t + 3][i];
            PackU2 pk;
            pk.h2[0] = __float22bfloat162_rn(make_float2(f0, f1));
            pk.h2[1] = __float22bfloat162_rn(make_float2(f2, f3));
            *(uint2*)&dst[tq * 4] = pk.u2;
        }
    }
}

// ---------------------------------------------------------------------------
// gemmG (+inline suffix scan): per (bh, ks):
//   scan: a_t = w_t * prod_{u>t} f_u over full S (8 KB fw read, in-LDS scan);
//         fill sAv with this block's 512-t slice; ks==0 writes fall/suma.
//   GEMM: G_part = sum_{t in slice} a_t * x_t x_t^T via bf16 MFMA 32x32x16.
//   svp[ks] partial of s_vec = sum_t a_t x_t (no atomics, summed in final).
// ---------------------------------------------------------------------------
__global__ __launch_bounds__(256, 2) void gemmG_kernel(
    const ushort* __restrict__ xTu, const float* __restrict__ fw,
    const float* __restrict__ router, const int* __restrict__ mem_id,
    float* __restrict__ Gp, float* __restrict__ svp,
    float* __restrict__ fallp, float* __restrict__ sumap)
{
    __shared__ ushort sA[128][BKP];   // 18.4 KB
    __shared__ ushort sXx[128][BKP];  // 18.4 KB
    __shared__ float  sAv[TS];        // 2 KB
    __shared__ float  sRed[256];      // 1 KB
    __shared__ float  sC[257];        // 1 KB
    __shared__ float  sR4[4];

    const int bh = blockIdx.x;
    const int b  = bh >> 3;
    const int ks = blockIdx.y;
    const int tid = threadIdx.x;

    // ---------------- inline scan (a2 logic) ----------------
    {
        float f[8];
        const float* frow = fw + (size_t)bh * S + tid * 8;
        const float4 fa = *(const float4*)frow;
        const float4 fb = *(const float4*)(frow + 4);
        f[0]=fa.x; f[1]=fa.y; f[2]=fa.z; f[3]=fa.w;
        f[4]=fb.x; f[5]=fb.y; f[6]=fb.z; f[7]=fb.w;

        float p = f[0];
        #pragma unroll
        for (int u = 1; u < 8; ++u) p *= f[u];
        sC[tid] = p;
        __syncthreads();

        for (int off = 1; off < 256; off <<= 1) {
            const float v = (tid + off < 256) ? sC[tid + off] : 1.f;
            __syncthreads();
            sC[tid] *= v;
            __syncthreads();
        }
        const float E = (tid < 255) ? sC[tid + 1] : 1.f;
        const int mid = mem_id[0];

        float aa[8];
        float s = 1.f;
        #pragma unroll
        for (int u = 7; u >= 0; --u) { aa[u] = s * E; s *= f[u]; }

        float lsum = 0.f;
        const bool mine = (tid >= ks * 64) && (tid < (ks + 1) * 64);
        #pragma unroll
        for (int u = 0; u < 8; ++u) {
            const int t = tid * 8 + u;
            const float w = router[((size_t)(b * S) + t) * NM + mid];
            const float av = aa[u] * w;
            if (mine) sAv[(tid - ks * 64) * 8 + u] = av;
            lsum += av;
        }
        if (ks == 0) {
            for (int off = 32; off; off >>= 1) lsum += __shfl_down(lsum, off);
            if ((tid & 63) == 0) sR4[tid >> 6] = lsum;
            __syncthreads();
            if (tid == 0) {
                sumap[bh] = sR4[0] + sR4[1] + sR4[2] + sR4[3];
                fallp[bh] = sC[0];
            }
        }
    }
    __syncthreads();

    // ---------------- MFMA main loop ----------------
    const int th = tid >> 7;
    const int i  = tid & 127;
    const ushort* xrow = xTu + (size_t)(b * D + i) * S;

    const int lane = tid & 63, wid = tid >> 6;
    const int wrow = wid >> 1, wcol = wid & 1;
    const int m = lane & 31, half = lane >> 5;

    float svacc = 0.f;
    f32x16 acc00 = {}, acc01 = {}, acc10 = {}, acc11 = {};

    for (int it = 0; it < TS / BK; ++it) {
        const int tloc = it * BK + th * 32;
        uint4 r[4];
        #pragma unroll
        for (int u = 0; u < 4; ++u)
            r[u] = *(const uint4*)(xrow + ks * TS + tloc + u * 8);
        float av[32];
        #pragma unroll
        for (int q = 0; q < 8; ++q) {
            const float4 a4 = *(const float4*)&sAv[tloc + q * 4];
            av[q*4+0] = a4.x; av[q*4+1] = a4.y; av[q*4+2] = a4.z; av[q*4+3] = a4.w;
        }
        __syncthreads();   // previous iter's MFMA reads done
        #pragma unroll
        for (int u = 0; u < 4; ++u) {
            *(uint4*)&sXx[i][th * 32 + u * 8] = r[u];
            const unsigned int w[4] = {r[u].x, r[u].y, r[u].z, r[u].w};
            unsigned int o[4];
            #pragma unroll
            for (int q = 0; q < 4; ++q) {
                const float f0 = __uint_as_float(w[q] << 16);
                const float f1 = __uint_as_float(w[q] & 0xffff0000u);
                const float g0 = f0 * av[u * 8 + 2 * q];
                const float g1 = f1 * av[u * 8 + 2 * q + 1];
                svacc += g0 + g1;
                PackU1 pk;
                pk.h2 = __float22bfloat162_rn(make_float2(g0, g1));
                o[q] = pk.u;
            }
            *(uint4*)&sA[i][th * 32 + u * 8] = make_uint4(o[0], o[1], o[2], o[3]);
        }
        __syncthreads();
        #pragma unroll
        for (int kstep = 0; kstep < 4; ++kstep) {
            const int koff = kstep * 16 + half * 8;
            const bf16x8 a0 = *(const bf16x8*)&sA [wrow * 64 +      m][koff];
            const bf16x8 a1 = *(const bf16x8*)&sA [wrow * 64 + 32 + m][koff];
            const bf16x8 b0 = *(const bf16x8*)&sXx[wcol * 64 +      m][koff];
            const bf16x8 b1 = *(const bf16x8*)&sXx[wcol * 64 + 32 + m][koff];
            acc00 = __builtin_amdgcn_mfma_f32_32x32x16_bf16(a0, b0, acc00, 0, 0, 0);
            acc01 = __builtin_amdgcn_mfma_f32_32x32x16_bf16(a0, b1, acc01, 0, 0, 0);
            acc10 = __builtin_amdgcn_mfma_f32_32x32x16_bf16(a1, b0, acc10, 0, 0, 0);
            acc11 = __builtin_amdgcn_mfma_f32_32x32x16_bf16(a1, b1, acc11, 0, 0, 0);
        }
    }

    // C/D layout (m74/m101): col = lane&31, row = (r&3)+8*(r>>2)+4*half
    float* gp = Gp + (size_t)(ks * B * H + bh) * (D * D);
    #pragma unroll
    for (int rg = 0; rg < 16; ++rg) {
        const int rowl = (rg & 3) + 8 * (rg >> 2) + 4 * half;
        gp[(wrow * 64 +      rowl) * D + wcol * 64 +      m] = acc00[rg];
        gp[(wrow * 64 +      rowl) * D + wcol * 64 + 32 + m] = acc01[rg];
        gp[(wrow * 64 + 32 + rowl) * D + wcol * 64 +      m] = acc10[rg];
        gp[(wrow * 64 + 32 + rowl) * D + wcol * 64 + 32 + m] = acc11[rg];
    }

    sRed[tid] = svacc;
    __syncthreads();
    if (tid < 128)
        svp[((size_t)ks * (B * H) + bh) * D + tid] = sRed[tid] + sRed[tid + 128];
}

// ---------------------------------------------------------------------------
// final: per (bh, col-half): C = Wk^T (G Wv) + u*bv^T + bk*w^T + suma*bk*bv^T
// + fall*M0. fp32 VALU; G symmetry -> all LDS reads row-major float4.
// ---------------------------------------------------------------------------
__global__ __launch_bounds__(256, 1) void final_kernel(
    const float* __restrict__ Gp, const float* __restrict__ Wk,
    const float* __restrict__ bk, const float* __restrict__ Wv,
    const float* __restrict__ bv, const float* __restrict__ svp,
    const float* __restrict__ fallp, const float* __restrict__ sumap,
    const float* __restrict__ M0, float* __restrict__ out)
{
    __shared__ float sA[128][132];
    __shared__ float sB[128][132];
    __shared__ float sSv[128];

    const int bh = blockIdx.x >> 1, hf = blockIdx.x & 1;
    const int h  = bh & 7;
    const int tid = threadIdx.x;

    #pragma unroll
    for (int q = 0; q < 16; ++q) {
        const int flat = q * 256 + tid;
        const int row = flat >> 5, c4 = (flat & 31) * 4;
        const size_t off = (size_t)bh * (D * D) + row * D + c4;
        float4 g = *(const float4*)&Gp[off];
        #pragma unroll
        for (int k = 1; k < KS; ++k) {
            const float4 g2 = *(const float4*)&Gp[(size_t)k * B * H * D * D + off];
            g.x += g2.x; g.y += g2.y; g.z += g2.z; g.w += g2.w;
        }
        *(float4*)&sA[row][c4] = g;
    }
    #pragma unroll
    for (int q = 0; q < 8; ++q) {
        const int flat = q * 256 + tid;
        const int l = flat >> 4, c4 = (flat & 15) * 4;
        *(float4*)&sB[l][c4] =
            *(const float4*)&Wv[(size_t)l * (D * H) + h * D + hf * 64 + c4];
    }
    if (tid < 128) {
        float s = 0.f;
        #pragma unroll
        for (int k = 0; k < KS; ++k)
            s += svp[((size_t)k * (B * H) + bh) * D + tid];
        sSv[tid] = s;
    }
    __syncthreads();

    const int r0 = (tid >> 3) * 4, c0 = (tid & 7) * 8;

    float P[4][8] = {};
    float wv8[8] = {};
    for (int l = 0; l < 128; ++l) {
        const float4 g  = *(const float4*)&sA[l][r0];
        const float4 w0 = *(const float4*)&sB[l][c0];
        const float4 w1 = *(const float4*)&sB[l][c0 + 4];
        const float sl = sSv[l];
        const float gg[4] = {g.x, g.y, g.z, g.w};
        const float ww[8] = {w0.x,w0.y,w0.z,w0.w,w1.x,w1.y,w1.z,w1.w};
        #pragma unroll
        for (int dr = 0; dr < 4; ++dr)
            #pragma unroll
            for (int dc = 0; dc < 8; ++dc) P[dr][dc] += gg[dr] * ww[dc];
        #pragma unroll
        for (int dc = 0; dc < 8; ++dc) wv8[dc] += sl * ww[dc];
    }
    __syncthreads();

    #pragma unroll
    for (int dr = 0; dr < 4; ++dr) {
        *(float4*)&sA[r0 + dr][c0]     = make_float4(P[dr][0], P[dr][1], P[dr][2], P[dr][3]);
        *(float4*)&sA[r0 + dr][c0 + 4] = make_float4(P[dr][4], P[dr][5], P[dr][6], P[dr][7]);
    }
    #pragma unroll
    for (int q = 0; q < 16; ++q) {
        const int flat = q * 256 + tid;
        const int k = flat >> 5, c4 = (flat & 31) * 4;
        *(float4*)&sB[k][c4] = *(const float4*)&Wk[(size_t)k * (D * H) + h * D + c4];
    }
    __syncthreads();

    float C[4][8] = {};
    float u4[4] = {};
    for (int k = 0; k < 128; ++k) {
        const float4 wk = *(const float4*)&sB[k][r0];
        const float4 p0 = *(const float4*)&sA[k][c0];
        const float4 p1 = *(const float4*)&sA[k][c0 + 4];
        const float svk = sSv[k];
        const float wkk[4] = {wk.x, wk.y, wk.z, wk.w};
        const float pp[8] = {p0.x,p0.y,p0.z,p0.w,p1.x,p1.y,p1.z,p1.w};
        #pragma unroll
        for (int di = 0; di < 4; ++di) {
            #pragma unroll
            for (int dc = 0; dc < 8; ++dc) C[di][dc] += wkk[di] * pp[dc];
            u4[di] += wkk[di] * svk;
        }
    }

    const float fallv = fallp[bh], sumav = sumap[bh];
    float bkv[4], bvv[8];
    #pragma unroll
    for (int di = 0; di < 4; ++di) bkv[di] = bk[h * D + r0 + di];
    #pragma unroll
    for (int dc = 0; dc < 8; ++dc) bvv[dc] = bv[h * D + hf * 64 + c0 + dc];

    const float* m0p = M0 + (size_t)bh * (D * D);
    float* op = out + (size_t)bh * (D * D);
    #pragma unroll
    for (int di = 0; di < 4; ++di)
        #pragma unroll
        for (int dc = 0; dc < 8; ++dc) {
            const size_t idx = (size_t)(r0 + di) * D + hf * 64 + c0 + dc;
            op[idx] = C[di][dc] + u4[di] * bvv[dc] + bkv[di] * wv8[dc]
                    + sumav * bkv[di] * bvv[dc] + fallv * m0p[idx];
        }
}

extern "C" void kernel_launch(void* const* d_in, const int* in_sizes, int n_in,
                              void* d_out, int out_size, void* d_ws, size_t ws_size,
                              hipStream_t stream) {
    const float* x      = (const float*)d_in[0];
    const float* M0     = (const float*)d_in[1];
    const float* router = (const float*)d_in[2];
    const int*   mem_id = (const int*)d_in[3];
    const float* Wk     = (const float*)d_in[4];
    const float* bk     = (const float*)d_in[5];
    const float* Wv     = (const float*)d_in[6];
    const float* bv     = (const float*)d_in[7];
    const float* Wf     = (const float*)d_in[8];
    const float* bf     = (const float*)d_in[9];
    float* out = (float*)d_out;

    char* ws = (char*)d_ws;
    ushort* xTu  = (ushort*)ws;                               // 8 MB   bf16 x^T
    float*  fw   = (float*)(ws + (8u << 20));                 // 1 MB   f gates
    float*  svp  = (float*)(ws + (9u << 20));                 // 256 KB s_vec partials
    float*  fall = (float*)(ws + (9u << 20) + (512u << 10));  // 512 B
    float*  suma = (float*)(ws + (9u << 20) + (512u << 10) + 4096);
    float*  Gp   = (float*)(ws + (10u << 20));                // 32 MB  G partials

    a1_kernel<<<256, 256, 0, stream>>>(x, Wf, bf, fw, xTu);
    gemmG_kernel<<<dim3(B * H, KS), 256, 0, stream>>>(xTu, fw, router, mem_id,
                                                      Gp, svp, fall, suma);
    final_kernel<<<2 * B * H, 256, 0, stream>>>(Gp, Wk, bk, Wv, bv, svp,
                                                fall, suma, M0, out);
}